// Round 3
// baseline (3342.054 us; speedup 1.0000x reference)
//
#include <hip/hip_runtime.h>
#include <hip/hip_bf16.h>
#include <stdint.h>

// ---------------------------------------------------------------------------
// NaiveLSTM: B=64, T=1024, I=512, H=512
//   phase 0: convert x->bf16; transpose W,U; init hist (slot0=0, rest=NaN
//            sentinel)
//   phase 1: xW = x @ W  (bf16 MFMA GEMM, global_load_lds staging)
//   phase 2: sequential LSTM. 8 groups x 8 batch rows x 16 blocks = 128
//            blocks. Under bid%8 XCD round-robin each group is XCD-local ->
//            h exchange through the SHARED XCD L2 with sc0 ops (~200cyc RT)
//            instead of the Infinity Cache (~700+). Producers double-store
//            (sc1 system + sc0 local); consumers poll sc0 and stickily fall
//            back to sc1 after 64 failed tries (correct for ANY placement).
// ---------------------------------------------------------------------------

typedef __attribute__((ext_vector_type(8))) short bf16x8;
typedef __attribute__((ext_vector_type(4))) float f32x4;

constexpr int T_STEPS = 1024;
constexpr int HS = 512;
constexpr int NGROUP = 8;                        // batch groups, 8 rows each
constexpr unsigned SENT = 0x7FC07FC0u;           // bf16 NaN pair
constexpr int HIST_SLOT_U32 = 8 * 512 / 2;       // 2048 u32 = 8KB per step/group

__device__ __forceinline__ unsigned short f2bf(float f) {
  unsigned u = __float_as_uint(f);
  u += 0x7fffu + ((u >> 16) & 1u);               // RNE
  return (unsigned short)(u >> 16);
}
__device__ __forceinline__ float bf_lo(unsigned u) { return __uint_as_float(u << 16); }
__device__ __forceinline__ float bf_hi(unsigned u) { return __uint_as_float(u & 0xffff0000u); }

__device__ __forceinline__ float fast_sig(float x) {
  return __builtin_amdgcn_rcpf(1.f + __expf(-x));
}
__device__ __forceinline__ float fast_tanh(float x) {
  return 2.f * __builtin_amdgcn_rcpf(1.f + __expf(-2.f * x)) - 1.f;
}

// ----- system-scope (LLC, cross-XCD safe) ops -----
__device__ __forceinline__ void stg_u32_llc(void* p, unsigned v) {
  asm volatile("global_store_dword %0, %1, off sc0 sc1" :: "v"(p), "v"(v) : "memory");
}
__device__ __forceinline__ void ldg_64B_llc(const void* p, uint4& a, uint4& b, uint4& c, uint4& d) {
  const char* q = (const char*)p;
  asm volatile(
      "global_load_dwordx4 %0, %4, off sc0 sc1\n\t"
      "global_load_dwordx4 %1, %5, off sc0 sc1\n\t"
      "global_load_dwordx4 %2, %6, off sc0 sc1\n\t"
      "global_load_dwordx4 %3, %7, off sc0 sc1\n\t"
      "s_waitcnt vmcnt(0)"
      : "=&v"(a), "=&v"(b), "=&v"(c), "=&v"(d)
      : "v"(q), "v"(q + 16), "v"(q + 32), "v"(q + 48)
      : "memory");
}
// ----- agent-scope (shared XCD L2) ops: valid when producer+consumer same XCD -----
__device__ __forceinline__ void stg_u32_l2(void* p, unsigned v) {
  asm volatile("global_store_dword %0, %1, off sc0" :: "v"(p), "v"(v) : "memory");
}
__device__ __forceinline__ void ldg_64B_l2(const void* p, uint4& a, uint4& b, uint4& c, uint4& d) {
  const char* q = (const char*)p;
  asm volatile(
      "global_load_dwordx4 %0, %4, off sc0\n\t"
      "global_load_dwordx4 %1, %5, off sc0\n\t"
      "global_load_dwordx4 %2, %6, off sc0\n\t"
      "global_load_dwordx4 %3, %7, off sc0\n\t"
      "s_waitcnt vmcnt(0)"
      : "=&v"(a), "=&v"(b), "=&v"(c), "=&v"(d)
      : "v"(q), "v"(q + 16), "v"(q + 32), "v"(q + 48)
      : "memory");
}

// ---------------------------------------------------------------------------
__global__ __launch_bounds__(256) void conv_f32_to_bf16(const float* __restrict__ in,
                                                        uint4* __restrict__ out, int n16) {
  int i = blockIdx.x * 256 + threadIdx.x;
  const int stride = gridDim.x * 256;
  for (; i < n16; i += stride) {
    float4 a = ((const float4*)in)[2 * i];
    float4 b = ((const float4*)in)[2 * i + 1];
    uint4 o;
    o.x = (unsigned)f2bf(a.x) | ((unsigned)f2bf(a.y) << 16);
    o.y = (unsigned)f2bf(a.z) | ((unsigned)f2bf(a.w) << 16);
    o.z = (unsigned)f2bf(b.x) | ((unsigned)f2bf(b.y) << 16);
    o.w = (unsigned)f2bf(b.z) | ((unsigned)f2bf(b.w) << 16);
    out[i] = o;
  }
}

// ---------------------------------------------------------------------------
__global__ __launch_bounds__(256) void transpose_to_bf16(const float* __restrict__ in,
                                                         unsigned short* __restrict__ out,
                                                         int R, int C) {
  __shared__ unsigned short tile[64][72];
  const int tx = threadIdx.x & 63, ty = threadIdx.x >> 6;
  const int c0 = blockIdx.x * 64, r0 = blockIdx.y * 64;
#pragma unroll
  for (int rr = ty; rr < 64; rr += 4)
    tile[rr][tx] = f2bf(in[(size_t)(r0 + rr) * C + c0 + tx]);
  __syncthreads();
#pragma unroll
  for (int cc = ty; cc < 64; cc += 4)
    out[(size_t)(c0 + cc) * R + r0 + tx] = tile[tx][cc];
}

// ---------------------------------------------------------------------------
// hist init: per group, slot 0 (h0) = 0.0, slots 1..1024 = sentinel.
// Runs EVERY launch (graph replays reuse the buffer).
// ---------------------------------------------------------------------------
__global__ __launch_bounds__(256) void init_hist(uint4* __restrict__ hist4) {
  const unsigned per_g = 1025u * 512u;           // uint4 per group region (8KB slots)
  const unsigned total = NGROUP * per_g;
  unsigned i = blockIdx.x * 256 + threadIdx.x;
  const unsigned stride = gridDim.x * 256;
  for (; i < total; i += stride) {
    const unsigned w = i % per_g;
    const unsigned v = (w < 512u) ? 0u : SENT;   // slot 0 = 512 uint4
    hist4[i] = make_uint4(v, v, v, v);
  }
}

// ---------------------------------------------------------------------------
// Phase 1 GEMM (unchanged): 128x128 tile, BK=64, global_load_lds staging.
// ---------------------------------------------------------------------------
__global__ __launch_bounds__(256, 1) void gemm_xw(const unsigned short* __restrict__ A,
                                                  const unsigned short* __restrict__ Bt,
                                                  unsigned short* __restrict__ C) {
  __shared__ __align__(16) char Al[128 * 128];
  __shared__ __align__(16) char Bl[128 * 128];
  const int tid = threadIdx.x, lane = tid & 63, wave = tid >> 6;
  const int n0 = blockIdx.x * 128;
  const size_t m0 = (size_t)blockIdx.y * 128;
  const int wm = wave >> 1, wn = wave & 1;
  f32x4 acc[4][4] = {};

  for (int ks = 0; ks < 8; ++ks) {
    const int k0 = ks * 64;
    if (ks) __syncthreads();
#pragma unroll
    for (int p = 0; p < 4; ++p) {
      const int off = p * 4096 + wave * 1024 + lane * 16;
      const int row = off >> 7, kb = off & 127;
      const unsigned short* ga = A + (m0 + row) * 512 + k0 + (kb >> 1);
      const unsigned short* gb = Bt + (size_t)(n0 + row) * 512 + k0 + (kb >> 1);
      __builtin_amdgcn_global_load_lds(
          (const __attribute__((address_space(1))) void*)ga,
          (__attribute__((address_space(3))) void*)(Al + p * 4096 + wave * 1024), 16, 0, 0);
      __builtin_amdgcn_global_load_lds(
          (const __attribute__((address_space(1))) void*)gb,
          (__attribute__((address_space(3))) void*)(Bl + p * 4096 + wave * 1024), 16, 0, 0);
    }
    __syncthreads();
#pragma unroll
    for (int kk = 0; kk < 2; ++kk) {
      const int kb = (kk * 32 + (lane >> 4) * 8) * 2;
      bf16x8 av[4], bv[4];
#pragma unroll
      for (int i = 0; i < 4; ++i)
        av[i] = *(const bf16x8*)(Al + (wm * 64 + i * 16 + (lane & 15)) * 128 + kb);
#pragma unroll
      for (int j = 0; j < 4; ++j)
        bv[j] = *(const bf16x8*)(Bl + (wn * 64 + j * 16 + (lane & 15)) * 128 + kb);
#pragma unroll
      for (int i = 0; i < 4; ++i)
#pragma unroll
        for (int j = 0; j < 4; ++j)
          acc[i][j] = __builtin_amdgcn_mfma_f32_16x16x32_bf16(av[i], bv[j], acc[i][j], 0, 0, 0);
    }
  }
#pragma unroll
  for (int i = 0; i < 4; ++i)
#pragma unroll
    for (int j = 0; j < 4; ++j) {
      const int col = n0 + wn * 64 + j * 16 + (lane & 15);
#pragma unroll
      for (int r = 0; r < 4; ++r) {
        const int row = wm * 64 + i * 16 + (lane >> 4) * 4 + r;
        C[(m0 + row) * (size_t)2048 + col] = f2bf(acc[i][j][r]);
      }
    }
}

// ---------------------------------------------------------------------------
// Phase 2: sequential LSTM. 128 blocks x 256 threads.
// group g = bid&7 (8 batch rows, rows g*8..g*8+8), bg = bid>>3 owns h-cols
// [bg*32, bg*32+32). Under bid%8 XCD round-robin, all 16 blocks of a group
// share one XCD L2 -> sc0 exchange. U fragments in registers (wave = gate).
// Threads 0..127 (waves 0,1) own poll/stage/elementwise/publish for the 8
// real rows; all 4 waves run MFMA (A rows 8-15 are zeros).
// ---------------------------------------------------------------------------
__global__ __launch_bounds__(256, 1) void lstm_seq(const unsigned* __restrict__ xW,       // bf16 pairs [65536][1024]
                                                   const unsigned short* __restrict__ Ut, // bf16 [2048][512]
                                                   const float* __restrict__ bias,        // [2048]
                                                   float* __restrict__ out,
                                                   unsigned* __restrict__ hist) {
  __shared__ __align__(16) unsigned short hl[2][16 * 512];  // dbuf, 32KB
  __shared__ float gl[4][16][32];                            // gate tiles, 8KB
  __shared__ float cl[16][32];                               // cell state, 2KB

  const int tid = threadIdx.x, lane = tid & 63, wave = tid >> 6;
  const int g = blockIdx.x & 7;
  const int bg = blockIdx.x >> 3;
  const int c0 = bg * 32;
  const int bm0 = g * 8;

  // ---- one-time: U^T fragments into registers (wave = gate) ----
  bf16x8 uf[16][2];
#pragma unroll
  for (int ks = 0; ks < 16; ++ks)
#pragma unroll
    for (int j = 0; j < 2; ++j)
      uf[ks][j] = *(const bf16x8*)(Ut +
          (size_t)(wave * 512 + c0 + j * 16 + (lane & 15)) * 512 + ks * 32 + (lane >> 4) * 8);

  if (tid < 128) ((float4*)cl)[tid] = make_float4(0.f, 0.f, 0.f, 0.f);
  // zero hl rows 8..15 of both buffers (read by MFMA, never re-written)
  for (int i = tid; i < 4096; i += 256) {
    const int buf = i >> 11, w = i & 2047;
    ((unsigned*)hl)[buf * 4096 + 2048 + w] = 0;
  }

  const int m = tid >> 4;          // batch row within group (valid < 8)
  const int np = (tid & 15) * 2;   // col pair within block's 32 cols
  float bs[4][2];
#pragma unroll
  for (int gg = 0; gg < 4; ++gg) {
    bs[gg][0] = bias[gg * 512 + c0 + np];
    bs[gg][1] = bias[gg * 512 + c0 + np + 1];
  }

  const int am = lane & 15;
  const int asw = (am & 7) << 4;
  const int kgb = (lane >> 4) * 16;
  const int rowb = (tid >> 4) * 1024;
  const int colb = (tid & 15) * 64;
  const int sw = ((tid >> 4) & 7) << 4;

  // prologue xW prefetch for t=0
  unsigned xwv[4];
  if (tid < 128) {
    const unsigned* base = xW + (size_t)(bm0 + m) * T_STEPS * 1024;
#pragma unroll
    for (int gg = 0; gg < 4; ++gg) xwv[gg] = base[(gg * 512 + c0 + np) >> 1];
  }

  int llc_mode = 0;  // sticky: 0 = local-L2 poll, 1 = LLC poll (any placement)
  __syncthreads();   // cl/hl init visible

  for (int t = 0; t < T_STEPS; ++t) {
    uint4 a, b, c, d;
    unsigned xwn[4];
    if (tid < 128) {
      // ---- poll h_t data (sc0 fast path, sticky sc1 fallback) ----
      const char* hb = (const char*)hist + (size_t)(g * 1025 + t) * 8192 + tid * 64;
      int tries = 0;
      for (;;) {
        if (llc_mode) ldg_64B_llc(hb, a, b, c, d);
        else          ldg_64B_l2(hb, a, b, c, d);
        const bool bad = (a.x == SENT) | (a.y == SENT) | (a.z == SENT) | (a.w == SENT) |
                         (b.x == SENT) | (b.y == SENT) | (b.z == SENT) | (b.w == SENT) |
                         (c.x == SENT) | (c.y == SENT) | (c.z == SENT) | (c.w == SENT) |
                         (d.x == SENT) | (d.y == SENT) | (d.z == SENT) | (d.w == SENT);
        if (!bad) break;
        if (!llc_mode && ++tries >= 64) llc_mode = 1;  // wrong placement -> LLC forever
      }
      // ---- prefetch NEXT step's xW early (covers HBM latency under compute) ----
      {
        const int tn = (t + 1 < T_STEPS) ? t + 1 : t;
        const unsigned* base = xW + ((size_t)(bm0 + m) * T_STEPS + tn) * 1024;
#pragma unroll
        for (int gg = 0; gg < 4; ++gg) xwn[gg] = base[(gg * 512 + c0 + np) >> 1];
      }
      // ---- stage h_t to LDS (swizzled) ----
      char* dst = (char*)hl[t & 1];
      *(uint4*)(dst + ((rowb + colb) ^ sw)) = a;
      *(uint4*)(dst + ((rowb + colb + 16) ^ sw)) = b;
      *(uint4*)(dst + ((rowb + colb + 32) ^ sw)) = c;
      *(uint4*)(dst + ((rowb + colb + 48) ^ sw)) = d;
    }
    __syncthreads();  // sync A

    // ---- h_t @ U slice: wave = gate, 4 dep-chains of 8 ----
    f32x4 p0 = {0.f, 0.f, 0.f, 0.f}, p1 = p0, q0 = p0, q1 = p0;
    const char* hbase = (const char*)hl[t & 1];
#pragma unroll
    for (int ks = 0; ks < 16; ks += 2) {
      bf16x8 av0 = *(const bf16x8*)(hbase + ((am * 1024 + ks * 64 + kgb) ^ asw));
      bf16x8 av1 = *(const bf16x8*)(hbase + ((am * 1024 + (ks + 1) * 64 + kgb) ^ asw));
      p0 = __builtin_amdgcn_mfma_f32_16x16x32_bf16(av0, uf[ks][0], p0, 0, 0, 0);
      q0 = __builtin_amdgcn_mfma_f32_16x16x32_bf16(av0, uf[ks][1], q0, 0, 0, 0);
      p1 = __builtin_amdgcn_mfma_f32_16x16x32_bf16(av1, uf[ks + 1][0], p1, 0, 0, 0);
      q1 = __builtin_amdgcn_mfma_f32_16x16x32_bf16(av1, uf[ks + 1][1], q1, 0, 0, 0);
    }
    const f32x4 acc0 = p0 + p1, acc1 = q0 + q1;
    {
      const int col = lane & 15, row4 = (lane >> 4) * 4;
#pragma unroll
      for (int r = 0; r < 4; ++r) {
        gl[wave][row4 + r][col] = acc0[r];
        gl[wave][row4 + r][col + 16] = acc1[r];
      }
    }
    __syncthreads();  // sync B

    if (tid < 128) {  // waves 0,1: elementwise + publish for the 8 real rows
      float h0, h1, cA, cB;
      {
        const int nc = np;
        const float xi = gl[0][m][nc] + bf_lo(xwv[0]) + bs[0][0];
        const float xf = gl[1][m][nc] + bf_lo(xwv[1]) + bs[1][0];
        const float xg = gl[2][m][nc] + bf_lo(xwv[2]) + bs[2][0];
        const float xo = gl[3][m][nc] + bf_lo(xwv[3]) + bs[3][0];
        const float it = fast_sig(xi), ft = fast_sig(xf);
        const float gt = fast_tanh(xg), ot = fast_sig(xo);
        cA = ft * cl[m][nc] + it * gt;
        h0 = ot * fast_tanh(cA);
        cl[m][nc] = cA;
      }
      {
        const int nc = np + 1;
        const float xi = gl[0][m][nc] + bf_hi(xwv[0]) + bs[0][1];
        const float xf = gl[1][m][nc] + bf_hi(xwv[1]) + bs[1][1];
        const float xg = gl[2][m][nc] + bf_hi(xwv[2]) + bs[2][1];
        const float xo = gl[3][m][nc] + bf_hi(xwv[3]) + bs[3][1];
        const float it = fast_sig(xi), ft = fast_sig(xf);
        const float gt = fast_tanh(xg), ot = fast_sig(xo);
        cB = ft * cl[m][nc] + it * gt;
        h1 = ot * fast_tanh(cB);
        cl[m][nc] = cB;
      }
      // publish h_{t+1}: sc1 (LLC, always-correct) + sc0 (fast local L2 copy)
      const unsigned hp = (unsigned)f2bf(h0) | ((unsigned)f2bf(h1) << 16);
      unsigned* haddr = hist + (size_t)(g * 1025 + t + 1) * HIST_SLOT_U32 + m * 256 + ((c0 + np) >> 1);
      stg_u32_llc(haddr, hp);
      stg_u32_l2(haddr, hp);
      // fp32 hidden_seq output (lazy)
      *(float2*)(out + ((size_t)(bm0 + m) * T_STEPS + t) * HS + c0 + np) = make_float2(h0, h1);
      if (t == T_STEPS - 1) {
        const size_t hs_total = (size_t)64 * T_STEPS * HS;
        *(float2*)(out + hs_total + (size_t)(bm0 + m) * HS + c0 + np) = make_float2(h0, h1);
        *(float2*)(out + hs_total + 64 * HS + (size_t)(bm0 + m) * HS + c0 + np) = make_float2(cA, cB);
      }
#pragma unroll
      for (int gg = 0; gg < 4; ++gg) xwv[gg] = xwn[gg];
    }
    // no end barrier: hl double-buffered; gl/cl rewrites fenced by sync A/B
  }
}

// ---------------------------------------------------------------------------
extern "C" void kernel_launch(void* const* d_in, const int* in_sizes, int n_in,
                              void* d_out, int out_size, void* d_ws, size_t ws_size,
                              hipStream_t stream) {
  const float* x = (const float*)d_in[0];
  const float* W = (const float*)d_in[1];
  const float* U = (const float*)d_in[2];
  const float* bias = (const float*)d_in[3];
  float* out = (float*)d_out;
  char* ws = (char*)d_ws;

  size_t off = 0;
  unsigned short* x_bf = (unsigned short*)(ws + off); off += (size_t)65536 * 512 * 2;       // 64MB
  unsigned short* Wt = (unsigned short*)(ws + off);   off += (size_t)2048 * 512 * 2;        // 2MB
  unsigned short* Ut = (unsigned short*)(ws + off);   off += (size_t)2048 * 512 * 2;        // 2MB
  unsigned* hist = (unsigned*)(ws + off);             off += (size_t)NGROUP * 1025 * 8192;  // 67MB
  unsigned short* xWb = (unsigned short*)(ws + off);  off += (size_t)65536 * 2048 * 2;      // 256MB
  if (ws_size < off) return;

  conv_f32_to_bf16<<<4096, 256, 0, stream>>>(x, (uint4*)x_bf, 33554432 / 8);
  transpose_to_bf16<<<dim3(32, 8), 256, 0, stream>>>(W, Wt, 512, 2048);
  transpose_to_bf16<<<dim3(32, 8), 256, 0, stream>>>(U, Ut, 512, 2048);
  init_hist<<<2048, 256, 0, stream>>>((uint4*)hist);
  gemm_xw<<<dim3(16, 512), 256, 0, stream>>>(x_bf, Wt, xWb);
  lstm_seq<<<128, 256, 0, stream>>>((const unsigned*)xWb, Ut, bias, out, hist);
}